// Round 7
// baseline (423.182 us; speedup 1.0000x reference)
//
#include <hip/hip_runtime.h>

// out[b,o,s,p] = bias[o] + sum_i W[o,i]*x[b,i,s,p]*(1 + 0.1*eps[n,o,i])
//   n = b*1024 + s*16 + p. B=8,I=64,S=64,P=16,O=128,N=8192. eps=256MB stream.
//
// Round 7: MEASUREMENT round (round-6 with the shift-precedence bug fixed).
// Kernel bit-identical to round 5. Shadow dispatch streams 256 MiB of cold
// poisoned d_ws (fake eps) into d_ws scratch; real kernel runs last.
// dur_us - 367 = true single-pass kernel time T.

#define NOISE 0.1f

__global__ __launch_bounds__(256) void noise_conv_kernel(
    const float* __restrict__ x,     // [8, 64, 64, 16]
    const float* __restrict__ W,     // [128, 64]
    const float* __restrict__ bias,  // [128]
    const float* __restrict__ eps,   // [8192, 128, 64]
    float* __restrict__ out)         // [8, 128, 64, 16]
{
    constexpr int I = 64, O = 128, SP = 1024;
    constexpr int NT = 8;   // n-rows per block
    constexpr int MH = 4;   // m-steps (16 o each) -> 64 o per block
    constexpr int NOUT = NT * MH * 16;  // 512 outputs per block
    __shared__ float lds_x[NT * I];     // 2 KB
    __shared__ float lds_p[NOUT * 17];  // partials, 17-dword pitch, 34 KB

    const int tid = threadIdx.x;
    const int g = tid >> 4;   // 0..15
    const int l = tid & 15;   // lane-in-row: i = 4l..4l+3

    const int mh = blockIdx.x & 1;   // o-half
    const int ns = blockIdx.x >> 1;  // n-slab
    const int n0  = ns * NT;
    const int b   = n0 >> 10;
    const int sp0 = n0 & 1023;
    const int o_base = mh * 64;

    // Stage x[n0+dn][i] into LDS (32B contiguous runs, one-time).
    const float* xb = x + b * (I * SP) + sp0;
    #pragma unroll
    for (int e = tid; e < NT * I; e += 256) {
        int i = e >> 3, dn = e & 7;
        lds_x[dn * I + i] = xb[i * SP + dn];
    }

    // W fragments: wf[m] = W[o_base + m*16 + g][4l..4l+3]
    float4 wf[MH];
    #pragma unroll
    for (int k = 0; k < MH; ++k)
        wf[k] = *(const float4*)(W + (o_base + k * 16 + g) * I + l * 4);

    __syncthreads();

    const float* eps_base = eps + (size_t)n0 * 8192 + (o_base + g) * 64 + l * 4;

    #pragma unroll
    for (int dn = 0; dn < NT; ++dn) {
        const float4 xv = *(const float4*)(lds_x + dn * I + l * 4);
        const float* ep = eps_base + dn * 8192;
        #pragma unroll
        for (int m = 0; m < MH; ++m) {
            float4 e4 = *(const float4*)(ep + m * 1024);
            float4 w4 = wf[m];
            float wx0 = w4.x * xv.x, wx1 = w4.y * xv.y,
                  wx2 = w4.z * xv.z, wx3 = w4.w * xv.w;
            float s = (wx0 + wx1) + (wx2 + wx3);
            float t = fmaf(wx3, e4.w,
                      fmaf(wx2, e4.z,
                      fmaf(wx1, e4.y, wx0 * e4.x)));
            float acc = fmaf(NOISE, t, s);
            lds_p[((dn * MH + m) * 16 + g) * 17 + l] = acc;
        }
    }
    __syncthreads();

    float* ob = out + b * (O * SP) + sp0;
    #pragma unroll
    for (int r = 0; r < 2; ++r) {
        int ol = tid + r * 256;
        const float* pp = lds_p + ol * 17;
        float ssum = 0.f;
        #pragma unroll
        for (int j = 0; j < 16; ++j) ssum += pp[j];
        int gg = ol & 15, mm = (ol >> 4) & 3, dn = ol >> 6;
        int o = o_base + mm * 16 + gg;
        ob[o * SP + dn] = ssum + bias[o];
    }
}

extern "C" void kernel_launch(void* const* d_in, const int* in_sizes, int n_in,
                              void* d_out, int out_size, void* d_ws, size_t ws_size,
                              hipStream_t stream) {
    const float* x    = (const float*)d_in[0];  // 524288
    const float* W    = (const float*)d_in[1];  // 8192
    const float* bias = (const float*)d_in[2];  // 128
    const float* eps  = (const float*)d_in[3];  // 67108864
    float* out = (float*)d_out;                 // 1048576

    // Shadow probe: identical kernel, cold 256 MiB of d_ws as eps, scratch out.
    // (0xAA-pattern floats are tiny denormals: numerically safe.)
    if (ws_size >= ((size_t)772 << 20)) {
        const float* fake_eps = (const float*)d_ws;                          // 256 MiB
        float*       fake_out = (float*)((char*)d_ws + ((size_t)768 << 20)); // 4 MiB
        noise_conv_kernel<<<2048, 256, 0, stream>>>(x, W, bias, fake_eps, fake_out);
    }

    // Real kernel (runs last; d_out correct as in round 5).
    noise_conv_kernel<<<2048, 256, 0, stream>>>(x, W, bias, eps, out);
}